// Round 19
// baseline (570.377 us; speedup 1.0000x reference)
//
#include <hip/hip_runtime.h>

#define NREL 8

typedef __attribute__((ext_vector_type(8))) short bf16x8;
typedef __attribute__((ext_vector_type(4))) float f32x4;

__device__ inline ushort f2bf(float f)
{
    union { float f; unsigned u; } v; v.f = f;
    unsigned r = v.u + 0x7FFF + ((v.u >> 16) & 1);   // RNE
    return (ushort)(r >> 16);
}

__device__ inline unsigned cvtpk(float lo, float hi)
{
    unsigned r;
    asm("v_cvt_pk_bf16_f32 %0, %1, %2" : "=v"(r) : "v"(lo), "v"(hi));
    return r;
}

// ---------------------------------------------------------------------------
// prep1: zero cnt + zero degree-hist + conv_x + conv_wf (one kernel).
// ---------------------------------------------------------------------------
__global__ __launch_bounds__(256) void prep1(
    float4* __restrict__ cntz, int cnt4, int* __restrict__ hist,
    const float* __restrict__ x, ushort* __restrict__ xb, int nx4,
    const float* __restrict__ W1, const float* __restrict__ root1,
    ushort* __restrict__ Wf1,
    const float* __restrict__ W2, const float* __restrict__ root2,
    ushort* __restrict__ Wf2)
{
    int tid = blockIdx.x * 256 + threadIdx.x;
    int stride = gridDim.x * 256;

    for (int i = tid; i < cnt4; i += stride)
        cntz[i] = make_float4(0.f, 0.f, 0.f, 0.f);
    if (tid < 512) hist[tid] = 0;

    for (int i = tid; i < nx4; i += stride) {
        float4 v = ((const float4*)x)[i];
        ushort4 o;
        o.x = f2bf(v.x); o.y = f2bf(v.y); o.z = f2bf(v.z); o.w = f2bf(v.w);
        ((ushort4*)xb)[i] = o;
    }

    const int WFN = 128 * 1152;
    for (int i = tid; i < 2 * WFN; i += stride) {
        int half = (i >= WFN);
        int j = half ? i - WFN : i;
        const float* W    = half ? W2 : W1;
        const float* root = half ? root2 : root1;
        ushort* Wf        = half ? Wf2 : Wf1;
        int f = j >> 9;
        int within = j & 511;
        int l = within >> 3;
        int jj = within & 7;
        int rs = f >> 5;
        int kk = (f >> 3) & 3;
        int n  = f & 7;
        int col = (n << 4) | (l & 15);
        int kl  = kk * 32 + (l >> 4) * 8 + jj;
        float v = (rs < 8) ? W[rs * 16384 + kl * 128 + col]
                           : root[kl * 128 + col];
        Wf[j] = f2bf(v);
    }
}

// ---------------------------------------------------------------------------
// CSR build chain
// ---------------------------------------------------------------------------
__global__ __launch_bounds__(256) void count_edges(
    const int* __restrict__ ei, const int* __restrict__ et,
    int* __restrict__ cnt, int E, int N)
{
    int e = blockIdx.x * 256 + threadIdx.x;
    if (e < E) {
        int d = ei[E + e];
        int r = et[e];
        atomicAdd(&cnt[r * N + d], 1);
    }
}

__global__ __launch_bounds__(256) void scan1f(
    const int* __restrict__ cnt, float* __restrict__ invc8,
    int* __restrict__ part, int* __restrict__ bsum, int N)
{
    __shared__ int tmp[256];
    int d = blockIdx.x * 256 + threadIdx.x;
    int s = 0;
    if (d < N) {
        #pragma unroll
        for (int r = 0; r < NREL; r++) {
            int c = cnt[r * N + d];
            s += c;
            invc8[(size_t)d * 8 + r] = (c > 0) ? 1.f / (float)c : 0.f;
        }
    }
    int v = s;
    tmp[threadIdx.x] = v;
    __syncthreads();
    for (int off = 1; off < 256; off <<= 1) {
        int t = (threadIdx.x >= off) ? tmp[threadIdx.x - off] : 0;
        __syncthreads();
        tmp[threadIdx.x] += t;
        __syncthreads();
    }
    if (d < N) part[d] = tmp[threadIdx.x] - v;
    if (threadIdx.x == 255) bsum[blockIdx.x] = tmp[255];
}

__global__ __launch_bounds__(1024) void scan2(int* __restrict__ bsum, int nb)
{
    __shared__ int tmp[1024];
    int tid = threadIdx.x;
    int v = (tid < nb) ? bsum[tid] : 0;
    tmp[tid] = v;
    __syncthreads();
    for (int off = 1; off < 1024; off <<= 1) {
        int t = (tid >= off) ? tmp[tid - off] : 0;
        __syncthreads();
        tmp[tid] += t;
        __syncthreads();
    }
    if (tid < nb) bsum[tid] = tmp[tid] - v;
}

__global__ __launch_bounds__(256) void scan3(
    const int* __restrict__ part, const int* __restrict__ bsum,
    int* __restrict__ rowptr, int* __restrict__ cursor, int n, int E)
{
    int i = blockIdx.x * 256 + threadIdx.x;
    if (i < n) {
        int v = part[i] + bsum[blockIdx.x];
        rowptr[i] = v;
        cursor[i] = v;
    }
    if (i == 0) rowptr[n] = E;
}

__global__ __launch_bounds__(256) void fill_csr(
    const int* __restrict__ ei, const int* __restrict__ et,
    int* __restrict__ cursor, int* __restrict__ spk, int E)
{
    int e = blockIdx.x * 256 + threadIdx.x;
    if (e < E) {
        int d = ei[E + e];
        int pos = atomicAdd(&cursor[d], 1);
        spk[pos] = (ei[e] << 8) | et[e];
    }
}

// ---------------------------------------------------------------------------
// Degree-sorted row permutation (round-18): counting sort by degree so each
// fused block gets 32 uniform-degree rows -> no straggler wave at the
// barrier. Per-row arithmetic & order unchanged -> bit-identical output.
// ---------------------------------------------------------------------------
__global__ __launch_bounds__(256) void deg_hist(
    const int* __restrict__ rowptr, int* __restrict__ hist, int N)
{
    int d = blockIdx.x * 256 + threadIdx.x;
    if (d < N) {
        int deg = rowptr[d + 1] - rowptr[d];
        if (deg > 511) deg = 511;
        atomicAdd(&hist[deg], 1);
    }
}

__global__ __launch_bounds__(512) void hist_scan(int* __restrict__ hist)
{
    __shared__ int tmp[512];
    int tid = threadIdx.x;
    int v = hist[tid];
    tmp[tid] = v;
    __syncthreads();
    for (int off = 1; off < 512; off <<= 1) {
        int t = (tid >= off) ? tmp[tid - off] : 0;
        __syncthreads();
        tmp[tid] += t;
        __syncthreads();
    }
    hist[tid] = tmp[tid] - v;   // exclusive prefix -> bin cursors
}

__global__ __launch_bounds__(256) void perm_fill(
    const int* __restrict__ rowptr, int* __restrict__ bincur,
    int* __restrict__ perm, int N)
{
    int d = blockIdx.x * 256 + threadIdx.x;
    if (d < N) {
        int deg = rowptr[d + 1] - rowptr[d];
        if (deg > 511) deg = 511;
        int pos = atomicAdd(&bincur[deg], 1);
        perm[pos] = d;
    }
}

// ---------------------------------------------------------------------------
// FUSED gather + MFMA (+ layer-2 classifier), v7 (round-18).
// vs round-17: (a) spk prefetch reverted (null result, tangled codegen);
// (b) embt stride 128->132 floats (banks (row*4+col)%32: classifier reads
// conflict-free, stores 2-way=free; was 4-way, +1.8M conflicts);
// (c) degree-sorted rows via perm[] (straggler -> mean).
// ---------------------------------------------------------------------------
__global__ __launch_bounds__(1024, 8) void fused_layer(
    const ushort* __restrict__ Xb, const int* __restrict__ rowptr,
    const int* __restrict__ spk, const float* __restrict__ invc8,
    const int* __restrict__ perm,
    const ushort* __restrict__ Wf, const float* __restrict__ bias,
    float* __restrict__ Ofp, ushort* __restrict__ Obf,
    const float* __restrict__ Wc, const float* __restrict__ bc,
    float* __restrict__ outC, int N, int relu)
{
    __shared__ ushort lds[8 * 32 * 128];   // 64 KB A-tile; reused as embt
    __shared__ f32x4 pscr[2][512];         // 16 KB partial accumulators

    int wid  = threadIdx.x >> 6;           // 0..15
    int lane = threadIdx.x & 63;
    int blk0 = blockIdx.x * 32;
    int lane4 = lane << 2;

    // ---------------- phase 1: gather TWO rows per wave ----------------
    #pragma unroll 1
    for (int rr = 0; rr < 2; rr++) {
        int lrow32 = wid * 2 + rr;
        int idx = blk0 + lrow32;
        int d = (idx < N) ? perm[idx] : -1;

        float2 a0 = {0.f, 0.f}, a1 = {0.f, 0.f}, a2 = {0.f, 0.f}, a3 = {0.f, 0.f};
        float2 a4 = {0.f, 0.f}, a5 = {0.f, 0.f}, a6 = {0.f, 0.f}, a7 = {0.f, 0.f};

        #define ROWLD(SP) \
            (*(const unsigned*)((const char*)Xb + (unsigned)((SP) | lane4)))
        #define CONSUME(P, U)                                               \
        {                                                                   \
            union { unsigned u; float f; } lo, hi;                          \
            lo.u = (U) << 16; hi.u = (U) & 0xFFFF0000u;                     \
            switch ((P) & 0xFF) {                                           \
                case 0: a0.x += lo.f; a0.y += hi.f; break;                  \
                case 1: a1.x += lo.f; a1.y += hi.f; break;                  \
                case 2: a2.x += lo.f; a2.y += hi.f; break;                  \
                case 3: a3.x += lo.f; a3.y += hi.f; break;                  \
                case 4: a4.x += lo.f; a4.y += hi.f; break;                  \
                case 5: a5.x += lo.f; a5.y += hi.f; break;                  \
                case 6: a6.x += lo.f; a6.y += hi.f; break;                  \
                default: a7.x += lo.f; a7.y += hi.f; break;                 \
            }                                                               \
        }

        if (d >= 0) {
            int beg = rowptr[d], end = rowptr[d + 1];
            int i = beg;
            for (; i + 8 <= end; i += 8) {
                int pk8 = spk[i + (lane & 7)];
                int p0 = __builtin_amdgcn_readlane(pk8, 0);
                int p1 = __builtin_amdgcn_readlane(pk8, 1);
                int p2 = __builtin_amdgcn_readlane(pk8, 2);
                int p3 = __builtin_amdgcn_readlane(pk8, 3);
                int p4 = __builtin_amdgcn_readlane(pk8, 4);
                int p5 = __builtin_amdgcn_readlane(pk8, 5);
                int p6 = __builtin_amdgcn_readlane(pk8, 6);
                int p7 = __builtin_amdgcn_readlane(pk8, 7);
                unsigned u0 = ROWLD(p0 & 0xFFFFFF00);
                unsigned u1 = ROWLD(p1 & 0xFFFFFF00);
                unsigned u2 = ROWLD(p2 & 0xFFFFFF00);
                unsigned u3 = ROWLD(p3 & 0xFFFFFF00);
                unsigned u4 = ROWLD(p4 & 0xFFFFFF00);
                unsigned u5 = ROWLD(p5 & 0xFFFFFF00);
                unsigned u6 = ROWLD(p6 & 0xFFFFFF00);
                unsigned u7 = ROWLD(p7 & 0xFFFFFF00);
                CONSUME(p0, u0);
                CONSUME(p1, u1);
                CONSUME(p2, u2);
                CONSUME(p3, u3);
                CONSUME(p4, u4);
                CONSUME(p5, u5);
                CONSUME(p6, u6);
                CONSUME(p7, u7);
            }
            for (; i + 4 <= end; i += 4) {
                int pk4 = spk[i + (lane & 3)];
                int p0 = __builtin_amdgcn_readlane(pk4, 0);
                int p1 = __builtin_amdgcn_readlane(pk4, 1);
                int p2 = __builtin_amdgcn_readlane(pk4, 2);
                int p3 = __builtin_amdgcn_readlane(pk4, 3);
                unsigned u0 = ROWLD(p0 & 0xFFFFFF00);
                unsigned u1 = ROWLD(p1 & 0xFFFFFF00);
                unsigned u2 = ROWLD(p2 & 0xFFFFFF00);
                unsigned u3 = ROWLD(p3 & 0xFFFFFF00);
                CONSUME(p0, u0);
                CONSUME(p1, u1);
                CONSUME(p2, u2);
                CONSUME(p3, u3);
            }
            for (; i < end; i++) {
                int p = __builtin_amdgcn_readfirstlane(spk[i]);
                unsigned u = ROWLD(p & 0xFFFFFF00);
                CONSUME(p, u);
            }
        }
        #undef CONSUME
        #undef ROWLD

        f32x4 iv0 = {0.f, 0.f, 0.f, 0.f}, iv1 = {0.f, 0.f, 0.f, 0.f};
        if (d >= 0) {
            iv0 = *(const f32x4*)&invc8[(size_t)d * 8];
            iv1 = *(const f32x4*)&invc8[(size_t)d * 8 + 4];
        }
        unsigned swz = (unsigned)(lrow32 & 7) << 4;
        char* rowbase = (char*)lds + (lrow32 << 8);
        unsigned wroff = (((unsigned)lane << 2)) ^ swz;
        #define WR2(R, A, IV)                                               \
        {                                                                   \
            unsigned pk = cvtpk(A.x * (IV), A.y * (IV));                    \
            *(unsigned*)(rowbase + (R << 13) + wroff) = pk;                 \
        }
        WR2(0, a0, iv0[0]) WR2(1, a1, iv0[1]) WR2(2, a2, iv0[2]) WR2(3, a3, iv0[3])
        WR2(4, a4, iv1[0]) WR2(5, a5, iv1[1]) WR2(6, a6, iv1[2]) WR2(7, a7, iv1[3])
        #undef WR2
    }
    __syncthreads();

    // ---------------- phase 2: K-split MFMA, 2 row-groups per B ----------------
    int lrow = lane & 15;
    int kgrp = lane >> 4;
    unsigned swzR = (unsigned)(lrow & 7) << 4;
    const bf16x8* Wf8 = (const bf16x8*)Wf;
    int n0    = wid & 7;
    int upper = wid >> 3;

    f32x4 acc0 = {0.f, 0.f, 0.f, 0.f};
    f32x4 acc1 = {0.f, 0.f, 0.f, 0.f};
    const char* ldsb = (const char*)lds;

    int rs0 = upper * 4;
    #pragma unroll 1
    for (int rs = rs0; rs < rs0 + 4; rs++) {
        const bf16x8* Bp = Wf8 + (size_t)rs * 2048 + (size_t)n0 * 64 + lane;
        bf16x8 b0 = Bp[0];
        bf16x8 b1 = Bp[512];
        bf16x8 b2 = Bp[1024];
        bf16x8 b3 = Bp[1536];
        const char* ab0 = ldsb + (rs << 13) + ((0 + lrow) << 8);
        const char* ab1 = ldsb + (rs << 13) + ((16 + lrow) << 8);
        {
            bf16x8 a0 = *(const bf16x8*)(ab0 + ((unsigned)(0 * 64 + kgrp * 16) ^ swzR));
            bf16x8 a1 = *(const bf16x8*)(ab0 + ((unsigned)(1 * 64 + kgrp * 16) ^ swzR));
            bf16x8 a2 = *(const bf16x8*)(ab0 + ((unsigned)(2 * 64 + kgrp * 16) ^ swzR));
            bf16x8 a3 = *(const bf16x8*)(ab0 + ((unsigned)(3 * 64 + kgrp * 16) ^ swzR));
            acc0 = __builtin_amdgcn_mfma_f32_16x16x32_bf16(a0, b0, acc0, 0, 0, 0);
            acc0 = __builtin_amdgcn_mfma_f32_16x16x32_bf16(a1, b1, acc0, 0, 0, 0);
            acc0 = __builtin_amdgcn_mfma_f32_16x16x32_bf16(a2, b2, acc0, 0, 0, 0);
            acc0 = __builtin_amdgcn_mfma_f32_16x16x32_bf16(a3, b3, acc0, 0, 0, 0);
        }
        {
            bf16x8 a0 = *(const bf16x8*)(ab1 + ((unsigned)(0 * 64 + kgrp * 16) ^ swzR));
            bf16x8 a1 = *(const bf16x8*)(ab1 + ((unsigned)(1 * 64 + kgrp * 16) ^ swzR));
            bf16x8 a2 = *(const bf16x8*)(ab1 + ((unsigned)(2 * 64 + kgrp * 16) ^ swzR));
            bf16x8 a3 = *(const bf16x8*)(ab1 + ((unsigned)(3 * 64 + kgrp * 16) ^ swzR));
            acc1 = __builtin_amdgcn_mfma_f32_16x16x32_bf16(a0, b0, acc1, 0, 0, 0);
            acc1 = __builtin_amdgcn_mfma_f32_16x16x32_bf16(a1, b1, acc1, 0, 0, 0);
            acc1 = __builtin_amdgcn_mfma_f32_16x16x32_bf16(a2, b2, acc1, 0, 0, 0);
            acc1 = __builtin_amdgcn_mfma_f32_16x16x32_bf16(a3, b3, acc1, 0, 0, 0);
        }
    }
    {   // root source from global Xb (permuted rows)
        int i0 = blk0 + lrow;      if (i0 >= N) i0 = N - 1;
        int i1 = blk0 + 16 + lrow; if (i1 >= N) i1 = N - 1;
        int arow0 = perm[i0];
        int arow1 = perm[i1];
        const ushort* A0 = Xb + (size_t)arow0 * 128;
        const ushort* A1 = Xb + (size_t)arow1 * 128;
        const bf16x8* Bp = Wf8 + (size_t)8 * 2048 + (size_t)n0 * 64 + lane;
        int kkb = upper * 2;
        bf16x8 b0 = Bp[(kkb + 0) * 512];
        bf16x8 b1 = Bp[(kkb + 1) * 512];
        bf16x8 a00 = *(const bf16x8*)(A0 + (kkb + 0) * 32 + kgrp * 8);
        bf16x8 a01 = *(const bf16x8*)(A0 + (kkb + 1) * 32 + kgrp * 8);
        bf16x8 a10 = *(const bf16x8*)(A1 + (kkb + 0) * 32 + kgrp * 8);
        bf16x8 a11 = *(const bf16x8*)(A1 + (kkb + 1) * 32 + kgrp * 8);
        acc0 = __builtin_amdgcn_mfma_f32_16x16x32_bf16(a00, b0, acc0, 0, 0, 0);
        acc0 = __builtin_amdgcn_mfma_f32_16x16x32_bf16(a01, b1, acc0, 0, 0, 0);
        acc1 = __builtin_amdgcn_mfma_f32_16x16x32_bf16(a10, b0, acc1, 0, 0, 0);
        acc1 = __builtin_amdgcn_mfma_f32_16x16x32_bf16(a11, b1, acc1, 0, 0, 0);
    }

    if (upper) {
        pscr[0][n0 * 64 + lane] = acc0;
        pscr[1][n0 * 64 + lane] = acc1;
    }
    __syncthreads();   // all A-tile reads complete after this

    if (!upper) {
        f32x4 p0 = pscr[0][n0 * 64 + lane];
        f32x4 p1 = pscr[1][n0 * 64 + lane];
        int col = n0 * 16 + lrow;
        float bv = bias[col];
        float* embt = (float*)lds;   // stride 132 (bank-conflict-free)
        #pragma unroll
        for (int rg = 0; rg < 2; rg++) {
            int lrowb = rg * 16 + kgrp * 4;
            f32x4 a = rg ? acc1 : acc0;
            f32x4 pp = rg ? p1 : p0;
            #pragma unroll
            for (int r = 0; r < 4; r++) {
                int idx = blk0 + lrowb + r;
                float v = a[r] + pp[r] + bv;
                if (relu) v = fmaxf(v, 0.f);
                if (outC) embt[(lrowb + r) * 132 + col] = v;
                if (idx < N) {
                    int row = perm[idx];
                    if (Ofp) Ofp[(size_t)row * 128 + col] = v;
                    if (Obf) Obf[(size_t)row * 128 + col] = f2bf(v);
                }
            }
        }
    }

    // ---------------- fused classifier (layer 2 only) ----------------
    if (outC) {
        __syncthreads();
        int t = threadIdx.x;
        if (t < 512) {
            int row = t >> 4;
            int c = t & 15;
            const float* er = (const float*)lds + row * 132;
            float acc2 = bc[c];
            #pragma unroll 8
            for (int k = 0; k < 128; k++) acc2 += er[k] * Wc[k * 16 + c];
            int idx = blk0 + row;
            if (idx < N) outC[(size_t)perm[idx] * 16 + c] = acc2;
        }
    }
}

static inline size_t align256(size_t x) { return (x + 255) & ~(size_t)255; }

extern "C" void kernel_launch(void* const* d_in, const int* in_sizes, int n_in,
                              void* d_out, int out_size, void* d_ws, size_t ws_size,
                              hipStream_t stream)
{
    const float* x     = (const float*)d_in[0];
    const int*   ei    = (const int*)d_in[1];
    const int*   et    = (const int*)d_in[2];
    const float* W1    = (const float*)d_in[3];
    const float* root1 = (const float*)d_in[4];
    const float* b1    = (const float*)d_in[5];
    const float* W2    = (const float*)d_in[6];
    const float* root2 = (const float*)d_in[7];
    const float* b2    = (const float*)d_in[8];
    const float* Wc    = (const float*)d_in[9];
    const float* bc    = (const float*)d_in[10];

    const int N = in_sizes[0] / 128;
    const int E = in_sizes[2];
    const int C = in_sizes[10];   // 16

    float* out = (float*)d_out;                 // [N,16]
    float* emb = out + (size_t)N * C;           // [N,128] fp32 (2nd output)

    size_t cntB  = align256((size_t)NREL * N * sizeof(int));
    size_t rpB   = align256((size_t)(N + 1) * sizeof(int));
    size_t curB  = align256((size_t)N * sizeof(int));
    size_t bsB   = align256((size_t)1024 * sizeof(int));
    size_t hsB   = align256((size_t)512 * sizeof(int));
    size_t pmB   = align256((size_t)N * sizeof(int));
    size_t invB  = align256((size_t)N * 8 * sizeof(float));
    size_t spkB  = align256((size_t)E * sizeof(int));
    size_t xbB   = align256((size_t)N * 128 * sizeof(ushort));
    size_t wtB   = align256((size_t)128 * 1152 * sizeof(ushort));

    char* p = (char*)d_ws;
    int*    cnt    = (int*)p;      p += cntB;
    int*    rowptr = (int*)p;      p += rpB;
    int*    cursor = (int*)p;      p += curB;
    int*    part   = (int*)p;      p += curB;
    int*    bsum   = (int*)p;      p += bsB;
    int*    hist   = (int*)p;      p += hsB;
    int*    perm   = (int*)p;      p += pmB;
    float*  invc8  = (float*)p;    p += invB;
    int*    spk    = (int*)p;      p += spkB;
    ushort* xb     = (ushort*)p;   p += xbB;
    ushort* hb     = (ushort*)p;   p += xbB;
    ushort* Wf1    = (ushort*)p;   p += wtB;
    ushort* Wf2    = (ushort*)p;

    dim3 blk(256);
    int gE    = (E + 255) / 256;
    int gN    = (N + 255) / 256;
    int gFus  = (N + 31) / 32;       // 1563
    long long cnt4 = (long long)NREL * N / 4;
    int nx4 = N * 32;

    // ---- prep: zeros + bf16 conversions (one kernel) ----
    prep1<<<2048, blk, 0, stream>>>((float4*)cnt, (int)cnt4, hist,
                                    x, xb, nx4,
                                    W1, root1, Wf1, W2, root2, Wf2);

    // ---- CSR build ----
    count_edges<<<gE, blk, 0, stream>>>(ei, et, cnt, E, N);
    scan1f<<<gN, blk, 0, stream>>>(cnt, invc8, part, bsum, N);
    scan2<<<1, 1024, 0, stream>>>(bsum, gN);
    scan3<<<gN, blk, 0, stream>>>(part, bsum, rowptr, cursor, N, E);
    fill_csr<<<gE, blk, 0, stream>>>(ei, et, cursor, spk, E);

    // ---- degree-sorted row permutation ----
    deg_hist<<<gN, blk, 0, stream>>>(rowptr, hist, N);
    hist_scan<<<1, 512, 0, stream>>>(hist);
    perm_fill<<<gN, blk, 0, stream>>>(rowptr, hist, perm, N);

    // ---- layer 1: fused gather+GEMM -> hb (bf16, relu) ----
    fused_layer<<<gFus, dim3(1024), 0, stream>>>(
        xb, rowptr, spk, invc8, perm, Wf1, b1, nullptr, hb,
        nullptr, nullptr, nullptr, N, 1);

    // ---- layer 2: fused gather+GEMM+classifier -> emb + out ----
    fused_layer<<<gFus, dim3(1024), 0, stream>>>(
        hb, rowptr, spk, invc8, perm, Wf2, b2, emb, nullptr,
        Wc, bc, out, N, 0);
}

// Round 20
// 235.980 us; speedup vs baseline: 2.4171x; 2.4171x over previous
//
#include <hip/hip_runtime.h>

#define NREL 8

typedef __attribute__((ext_vector_type(8))) short bf16x8;
typedef __attribute__((ext_vector_type(4))) float f32x4;

__device__ inline ushort f2bf(float f)
{
    union { float f; unsigned u; } v; v.f = f;
    unsigned r = v.u + 0x7FFF + ((v.u >> 16) & 1);   // RNE
    return (ushort)(r >> 16);
}

__device__ inline unsigned cvtpk(float lo, float hi)
{
    unsigned r;
    asm("v_cvt_pk_bf16_f32 %0, %1, %2" : "=v"(r) : "v"(lo), "v"(hi));
    return r;
}

// ---------------------------------------------------------------------------
// prep1: zero cnt + conv_x + conv_wf (one kernel).
// ---------------------------------------------------------------------------
__global__ __launch_bounds__(256) void prep1(
    float4* __restrict__ cntz, int cnt4,
    const float* __restrict__ x, ushort* __restrict__ xb, int nx4,
    const float* __restrict__ W1, const float* __restrict__ root1,
    ushort* __restrict__ Wf1,
    const float* __restrict__ W2, const float* __restrict__ root2,
    ushort* __restrict__ Wf2)
{
    int tid = blockIdx.x * 256 + threadIdx.x;
    int stride = gridDim.x * 256;

    for (int i = tid; i < cnt4; i += stride)
        cntz[i] = make_float4(0.f, 0.f, 0.f, 0.f);

    for (int i = tid; i < nx4; i += stride) {
        float4 v = ((const float4*)x)[i];
        ushort4 o;
        o.x = f2bf(v.x); o.y = f2bf(v.y); o.z = f2bf(v.z); o.w = f2bf(v.w);
        ((ushort4*)xb)[i] = o;
    }

    const int WFN = 128 * 1152;
    for (int i = tid; i < 2 * WFN; i += stride) {
        int half = (i >= WFN);
        int j = half ? i - WFN : i;
        const float* W    = half ? W2 : W1;
        const float* root = half ? root2 : root1;
        ushort* Wf        = half ? Wf2 : Wf1;
        int f = j >> 9;
        int within = j & 511;
        int l = within >> 3;
        int jj = within & 7;
        int rs = f >> 5;
        int kk = (f >> 3) & 3;
        int n  = f & 7;
        int col = (n << 4) | (l & 15);
        int kl  = kk * 32 + (l >> 4) * 8 + jj;
        float v = (rs < 8) ? W[rs * 16384 + kl * 128 + col]
                           : root[kl * 128 + col];
        Wf[j] = f2bf(v);
    }
}

// ---------------------------------------------------------------------------
// CSR build chain
// ---------------------------------------------------------------------------
__global__ __launch_bounds__(256) void count_edges(
    const int* __restrict__ ei, const int* __restrict__ et,
    int* __restrict__ cnt, int E, int N)
{
    int e = blockIdx.x * 256 + threadIdx.x;
    if (e < E) {
        int d = ei[E + e];
        int r = et[e];
        atomicAdd(&cnt[r * N + d], 1);
    }
}

__global__ __launch_bounds__(256) void scan1f(
    const int* __restrict__ cnt, float* __restrict__ invc8,
    int* __restrict__ part, int* __restrict__ bsum, int N)
{
    __shared__ int tmp[256];
    int d = blockIdx.x * 256 + threadIdx.x;
    int s = 0;
    if (d < N) {
        #pragma unroll
        for (int r = 0; r < NREL; r++) {
            int c = cnt[r * N + d];
            s += c;
            invc8[(size_t)d * 8 + r] = (c > 0) ? 1.f / (float)c : 0.f;
        }
    }
    int v = s;
    tmp[threadIdx.x] = v;
    __syncthreads();
    for (int off = 1; off < 256; off <<= 1) {
        int t = (threadIdx.x >= off) ? tmp[threadIdx.x - off] : 0;
        __syncthreads();
        tmp[threadIdx.x] += t;
        __syncthreads();
    }
    if (d < N) part[d] = tmp[threadIdx.x] - v;
    if (threadIdx.x == 255) bsum[blockIdx.x] = tmp[255];
}

__global__ __launch_bounds__(1024) void scan2(int* __restrict__ bsum, int nb)
{
    __shared__ int tmp[1024];
    int tid = threadIdx.x;
    int v = (tid < nb) ? bsum[tid] : 0;
    tmp[tid] = v;
    __syncthreads();
    for (int off = 1; off < 1024; off <<= 1) {
        int t = (tid >= off) ? tmp[tid - off] : 0;
        __syncthreads();
        tmp[tid] += t;
        __syncthreads();
    }
    if (tid < nb) bsum[tid] = tmp[tid] - v;
}

__global__ __launch_bounds__(256) void scan3(
    const int* __restrict__ part, const int* __restrict__ bsum,
    int* __restrict__ rowptr, int* __restrict__ cursor, int n, int E)
{
    int i = blockIdx.x * 256 + threadIdx.x;
    if (i < n) {
        int v = part[i] + bsum[blockIdx.x];
        rowptr[i] = v;
        cursor[i] = v;
    }
    if (i == 0) rowptr[n] = E;
}

__global__ __launch_bounds__(256) void fill_csr(
    const int* __restrict__ ei, const int* __restrict__ et,
    int* __restrict__ cursor, int* __restrict__ spk, int E)
{
    int e = blockIdx.x * 256 + threadIdx.x;
    if (e < E) {
        int d = ei[E + e];
        int pos = atomicAdd(&cursor[d], 1);
        spk[pos] = (ei[e] << 8) | et[e];
    }
}

// ---------------------------------------------------------------------------
// FUSED gather + MFMA (+ layer-2 classifier), v8 (round-20).
// = round-17 structure + the two clean round-18 fixes:
//   (a) spk prefetch reverted to straight 8-deep batches
//   (b) embt stride 132 floats -> classifier reads bank-conflict-free
// Degree-sort REVERTED (round-19: sort kernels cost ~300us in global-atomic
// contention AND perm scattered the output writes; net -334us regression).
// ---------------------------------------------------------------------------
__global__ __launch_bounds__(1024, 8) void fused_layer(
    const ushort* __restrict__ Xb, const int* __restrict__ rowptr,
    const int* __restrict__ spk, const float* __restrict__ invc8,
    const ushort* __restrict__ Wf, const float* __restrict__ bias,
    float* __restrict__ Ofp, ushort* __restrict__ Obf,
    const float* __restrict__ Wc, const float* __restrict__ bc,
    float* __restrict__ outC, int N, int relu)
{
    __shared__ ushort lds[8 * 32 * 128];   // 64 KB A-tile; reused as embt
    __shared__ f32x4 pscr[2][512];         // 16 KB partial accumulators

    int wid  = threadIdx.x >> 6;           // 0..15
    int lane = threadIdx.x & 63;
    int blk0 = blockIdx.x * 32;
    int lane4 = lane << 2;

    // ---------------- phase 1: gather TWO rows per wave ----------------
    #pragma unroll 1
    for (int rr = 0; rr < 2; rr++) {
        int lrow32 = wid * 2 + rr;
        int d = blk0 + lrow32;

        float2 a0 = {0.f, 0.f}, a1 = {0.f, 0.f}, a2 = {0.f, 0.f}, a3 = {0.f, 0.f};
        float2 a4 = {0.f, 0.f}, a5 = {0.f, 0.f}, a6 = {0.f, 0.f}, a7 = {0.f, 0.f};

        #define ROWLD(SP) \
            (*(const unsigned*)((const char*)Xb + (unsigned)((SP) | lane4)))
        #define CONSUME(P, U)                                               \
        {                                                                   \
            union { unsigned u; float f; } lo, hi;                          \
            lo.u = (U) << 16; hi.u = (U) & 0xFFFF0000u;                     \
            switch ((P) & 0xFF) {                                           \
                case 0: a0.x += lo.f; a0.y += hi.f; break;                  \
                case 1: a1.x += lo.f; a1.y += hi.f; break;                  \
                case 2: a2.x += lo.f; a2.y += hi.f; break;                  \
                case 3: a3.x += lo.f; a3.y += hi.f; break;                  \
                case 4: a4.x += lo.f; a4.y += hi.f; break;                  \
                case 5: a5.x += lo.f; a5.y += hi.f; break;                  \
                case 6: a6.x += lo.f; a6.y += hi.f; break;                  \
                default: a7.x += lo.f; a7.y += hi.f; break;                 \
            }                                                               \
        }

        if (d < N) {
            int beg = rowptr[d], end = rowptr[d + 1];
            int i = beg;
            for (; i + 8 <= end; i += 8) {
                int pk8 = spk[i + (lane & 7)];
                int p0 = __builtin_amdgcn_readlane(pk8, 0);
                int p1 = __builtin_amdgcn_readlane(pk8, 1);
                int p2 = __builtin_amdgcn_readlane(pk8, 2);
                int p3 = __builtin_amdgcn_readlane(pk8, 3);
                int p4 = __builtin_amdgcn_readlane(pk8, 4);
                int p5 = __builtin_amdgcn_readlane(pk8, 5);
                int p6 = __builtin_amdgcn_readlane(pk8, 6);
                int p7 = __builtin_amdgcn_readlane(pk8, 7);
                unsigned u0 = ROWLD(p0 & 0xFFFFFF00);
                unsigned u1 = ROWLD(p1 & 0xFFFFFF00);
                unsigned u2 = ROWLD(p2 & 0xFFFFFF00);
                unsigned u3 = ROWLD(p3 & 0xFFFFFF00);
                unsigned u4 = ROWLD(p4 & 0xFFFFFF00);
                unsigned u5 = ROWLD(p5 & 0xFFFFFF00);
                unsigned u6 = ROWLD(p6 & 0xFFFFFF00);
                unsigned u7 = ROWLD(p7 & 0xFFFFFF00);
                CONSUME(p0, u0);
                CONSUME(p1, u1);
                CONSUME(p2, u2);
                CONSUME(p3, u3);
                CONSUME(p4, u4);
                CONSUME(p5, u5);
                CONSUME(p6, u6);
                CONSUME(p7, u7);
            }
            for (; i + 4 <= end; i += 4) {
                int pk4 = spk[i + (lane & 3)];
                int p0 = __builtin_amdgcn_readlane(pk4, 0);
                int p1 = __builtin_amdgcn_readlane(pk4, 1);
                int p2 = __builtin_amdgcn_readlane(pk4, 2);
                int p3 = __builtin_amdgcn_readlane(pk4, 3);
                unsigned u0 = ROWLD(p0 & 0xFFFFFF00);
                unsigned u1 = ROWLD(p1 & 0xFFFFFF00);
                unsigned u2 = ROWLD(p2 & 0xFFFFFF00);
                unsigned u3 = ROWLD(p3 & 0xFFFFFF00);
                CONSUME(p0, u0);
                CONSUME(p1, u1);
                CONSUME(p2, u2);
                CONSUME(p3, u3);
            }
            for (; i < end; i++) {
                int p = __builtin_amdgcn_readfirstlane(spk[i]);
                unsigned u = ROWLD(p & 0xFFFFFF00);
                CONSUME(p, u);
            }
        }
        #undef CONSUME
        #undef ROWLD

        f32x4 iv0 = {0.f, 0.f, 0.f, 0.f}, iv1 = {0.f, 0.f, 0.f, 0.f};
        if (d < N) {
            iv0 = *(const f32x4*)&invc8[(size_t)d * 8];
            iv1 = *(const f32x4*)&invc8[(size_t)d * 8 + 4];
        }
        unsigned swz = (unsigned)(lrow32 & 7) << 4;
        char* rowbase = (char*)lds + (lrow32 << 8);
        unsigned wroff = (((unsigned)lane << 2)) ^ swz;
        #define WR2(R, A, IV)                                               \
        {                                                                   \
            unsigned pk = cvtpk(A.x * (IV), A.y * (IV));                    \
            *(unsigned*)(rowbase + (R << 13) + wroff) = pk;                 \
        }
        WR2(0, a0, iv0[0]) WR2(1, a1, iv0[1]) WR2(2, a2, iv0[2]) WR2(3, a3, iv0[3])
        WR2(4, a4, iv1[0]) WR2(5, a5, iv1[1]) WR2(6, a6, iv1[2]) WR2(7, a7, iv1[3])
        #undef WR2
    }
    __syncthreads();

    // ---------------- phase 2: K-split MFMA, 2 row-groups per B ----------------
    int lrow = lane & 15;
    int kgrp = lane >> 4;
    unsigned swzR = (unsigned)(lrow & 7) << 4;
    const bf16x8* Wf8 = (const bf16x8*)Wf;
    int n0    = wid & 7;
    int upper = wid >> 3;

    f32x4 acc0 = {0.f, 0.f, 0.f, 0.f};
    f32x4 acc1 = {0.f, 0.f, 0.f, 0.f};
    const char* ldsb = (const char*)lds;

    int rs0 = upper * 4;
    #pragma unroll 1
    for (int rs = rs0; rs < rs0 + 4; rs++) {
        const bf16x8* Bp = Wf8 + (size_t)rs * 2048 + (size_t)n0 * 64 + lane;
        bf16x8 b0 = Bp[0];
        bf16x8 b1 = Bp[512];
        bf16x8 b2 = Bp[1024];
        bf16x8 b3 = Bp[1536];
        const char* ab0 = ldsb + (rs << 13) + ((0 + lrow) << 8);
        const char* ab1 = ldsb + (rs << 13) + ((16 + lrow) << 8);
        {
            bf16x8 a0 = *(const bf16x8*)(ab0 + ((unsigned)(0 * 64 + kgrp * 16) ^ swzR));
            bf16x8 a1 = *(const bf16x8*)(ab0 + ((unsigned)(1 * 64 + kgrp * 16) ^ swzR));
            bf16x8 a2 = *(const bf16x8*)(ab0 + ((unsigned)(2 * 64 + kgrp * 16) ^ swzR));
            bf16x8 a3 = *(const bf16x8*)(ab0 + ((unsigned)(3 * 64 + kgrp * 16) ^ swzR));
            acc0 = __builtin_amdgcn_mfma_f32_16x16x32_bf16(a0, b0, acc0, 0, 0, 0);
            acc0 = __builtin_amdgcn_mfma_f32_16x16x32_bf16(a1, b1, acc0, 0, 0, 0);
            acc0 = __builtin_amdgcn_mfma_f32_16x16x32_bf16(a2, b2, acc0, 0, 0, 0);
            acc0 = __builtin_amdgcn_mfma_f32_16x16x32_bf16(a3, b3, acc0, 0, 0, 0);
        }
        {
            bf16x8 a0 = *(const bf16x8*)(ab1 + ((unsigned)(0 * 64 + kgrp * 16) ^ swzR));
            bf16x8 a1 = *(const bf16x8*)(ab1 + ((unsigned)(1 * 64 + kgrp * 16) ^ swzR));
            bf16x8 a2 = *(const bf16x8*)(ab1 + ((unsigned)(2 * 64 + kgrp * 16) ^ swzR));
            bf16x8 a3 = *(const bf16x8*)(ab1 + ((unsigned)(3 * 64 + kgrp * 16) ^ swzR));
            acc1 = __builtin_amdgcn_mfma_f32_16x16x32_bf16(a0, b0, acc1, 0, 0, 0);
            acc1 = __builtin_amdgcn_mfma_f32_16x16x32_bf16(a1, b1, acc1, 0, 0, 0);
            acc1 = __builtin_amdgcn_mfma_f32_16x16x32_bf16(a2, b2, acc1, 0, 0, 0);
            acc1 = __builtin_amdgcn_mfma_f32_16x16x32_bf16(a3, b3, acc1, 0, 0, 0);
        }
    }
    {   // root source from global Xb
        int arow0 = blk0 + lrow;      if (arow0 >= N) arow0 = N - 1;
        int arow1 = blk0 + 16 + lrow; if (arow1 >= N) arow1 = N - 1;
        const ushort* A0 = Xb + (size_t)arow0 * 128;
        const ushort* A1 = Xb + (size_t)arow1 * 128;
        const bf16x8* Bp = Wf8 + (size_t)8 * 2048 + (size_t)n0 * 64 + lane;
        int kkb = upper * 2;
        bf16x8 b0 = Bp[(kkb + 0) * 512];
        bf16x8 b1 = Bp[(kkb + 1) * 512];
        bf16x8 a00 = *(const bf16x8*)(A0 + (kkb + 0) * 32 + kgrp * 8);
        bf16x8 a01 = *(const bf16x8*)(A0 + (kkb + 1) * 32 + kgrp * 8);
        bf16x8 a10 = *(const bf16x8*)(A1 + (kkb + 0) * 32 + kgrp * 8);
        bf16x8 a11 = *(const bf16x8*)(A1 + (kkb + 1) * 32 + kgrp * 8);
        acc0 = __builtin_amdgcn_mfma_f32_16x16x32_bf16(a00, b0, acc0, 0, 0, 0);
        acc0 = __builtin_amdgcn_mfma_f32_16x16x32_bf16(a01, b1, acc0, 0, 0, 0);
        acc1 = __builtin_amdgcn_mfma_f32_16x16x32_bf16(a10, b0, acc1, 0, 0, 0);
        acc1 = __builtin_amdgcn_mfma_f32_16x16x32_bf16(a11, b1, acc1, 0, 0, 0);
    }

    if (upper) {
        pscr[0][n0 * 64 + lane] = acc0;
        pscr[1][n0 * 64 + lane] = acc1;
    }
    __syncthreads();   // all A-tile reads complete after this

    if (!upper) {
        f32x4 p0 = pscr[0][n0 * 64 + lane];
        f32x4 p1 = pscr[1][n0 * 64 + lane];
        int col = n0 * 16 + lrow;
        float bv = bias[col];
        float* embt = (float*)lds;   // stride 132 (bank-conflict-free)
        #pragma unroll
        for (int rg = 0; rg < 2; rg++) {
            int lrowb = rg * 16 + kgrp * 4;
            f32x4 a = rg ? acc1 : acc0;
            f32x4 pp = rg ? p1 : p0;
            #pragma unroll
            for (int r = 0; r < 4; r++) {
                int row = blk0 + lrowb + r;
                float v = a[r] + pp[r] + bv;
                if (relu) v = fmaxf(v, 0.f);
                if (outC) embt[(lrowb + r) * 132 + col] = v;
                if (row < N) {
                    if (Ofp) Ofp[(size_t)row * 128 + col] = v;
                    if (Obf) Obf[(size_t)row * 128 + col] = f2bf(v);
                }
            }
        }
    }

    // ---------------- fused classifier (layer 2 only) ----------------
    if (outC) {
        __syncthreads();
        int t = threadIdx.x;
        if (t < 512) {
            int row = t >> 4;
            int c = t & 15;
            const float* er = (const float*)lds + row * 132;
            float acc2 = bc[c];
            #pragma unroll 8
            for (int k = 0; k < 128; k++) acc2 += er[k] * Wc[k * 16 + c];
            int grow = blk0 + row;
            if (grow < N) outC[(size_t)grow * 16 + c] = acc2;
        }
    }
}

static inline size_t align256(size_t x) { return (x + 255) & ~(size_t)255; }

extern "C" void kernel_launch(void* const* d_in, const int* in_sizes, int n_in,
                              void* d_out, int out_size, void* d_ws, size_t ws_size,
                              hipStream_t stream)
{
    const float* x     = (const float*)d_in[0];
    const int*   ei    = (const int*)d_in[1];
    const int*   et    = (const int*)d_in[2];
    const float* W1    = (const float*)d_in[3];
    const float* root1 = (const float*)d_in[4];
    const float* b1    = (const float*)d_in[5];
    const float* W2    = (const float*)d_in[6];
    const float* root2 = (const float*)d_in[7];
    const float* b2    = (const float*)d_in[8];
    const float* Wc    = (const float*)d_in[9];
    const float* bc    = (const float*)d_in[10];

    const int N = in_sizes[0] / 128;
    const int E = in_sizes[2];
    const int C = in_sizes[10];   // 16

    float* out = (float*)d_out;                 // [N,16]
    float* emb = out + (size_t)N * C;           // [N,128] fp32 (2nd output)

    size_t cntB  = align256((size_t)NREL * N * sizeof(int));
    size_t rpB   = align256((size_t)(N + 1) * sizeof(int));
    size_t curB  = align256((size_t)N * sizeof(int));
    size_t bsB   = align256((size_t)1024 * sizeof(int));
    size_t invB  = align256((size_t)N * 8 * sizeof(float));
    size_t spkB  = align256((size_t)E * sizeof(int));
    size_t xbB   = align256((size_t)N * 128 * sizeof(ushort));
    size_t wtB   = align256((size_t)128 * 1152 * sizeof(ushort));

    char* p = (char*)d_ws;
    int*    cnt    = (int*)p;      p += cntB;
    int*    rowptr = (int*)p;      p += rpB;
    int*    cursor = (int*)p;      p += curB;
    int*    part   = (int*)p;      p += curB;
    int*    bsum   = (int*)p;      p += bsB;
    float*  invc8  = (float*)p;    p += invB;
    int*    spk    = (int*)p;      p += spkB;
    ushort* xb     = (ushort*)p;   p += xbB;
    ushort* hb     = (ushort*)p;   p += xbB;
    ushort* Wf1    = (ushort*)p;   p += wtB;
    ushort* Wf2    = (ushort*)p;

    dim3 blk(256);
    int gE    = (E + 255) / 256;
    int gN    = (N + 255) / 256;
    int gFus  = (N + 31) / 32;       // 1563
    long long cnt4 = (long long)NREL * N / 4;
    int nx4 = N * 32;

    // ---- prep: zeros + bf16 conversions (one kernel) ----
    prep1<<<2048, blk, 0, stream>>>((float4*)cnt, (int)cnt4,
                                    x, xb, nx4,
                                    W1, root1, Wf1, W2, root2, Wf2);

    // ---- CSR build ----
    count_edges<<<gE, blk, 0, stream>>>(ei, et, cnt, E, N);
    scan1f<<<gN, blk, 0, stream>>>(cnt, invc8, part, bsum, N);
    scan2<<<1, 1024, 0, stream>>>(bsum, gN);
    scan3<<<gN, blk, 0, stream>>>(part, bsum, rowptr, cursor, N, E);
    fill_csr<<<gE, blk, 0, stream>>>(ei, et, cursor, spk, E);

    // ---- layer 1: fused gather+GEMM -> hb (bf16, relu) ----
    fused_layer<<<gFus, dim3(1024), 0, stream>>>(
        xb, rowptr, spk, invc8, Wf1, b1, nullptr, hb,
        nullptr, nullptr, nullptr, N, 1);

    // ---- layer 2: fused gather+GEMM+classifier -> emb + out ----
    fused_layer<<<gFus, dim3(1024), 0, stream>>>(
        hb, rowptr, spk, invc8, Wf2, b2, emb, nullptr,
        Wc, bc, out, N, 0);
}

// Round 22
// 234.930 us; speedup vs baseline: 2.4279x; 1.0045x over previous
//
#include <hip/hip_runtime.h>

#define NREL 8

typedef __attribute__((ext_vector_type(8))) short bf16x8;
typedef __attribute__((ext_vector_type(4))) float f32x4;

__device__ inline ushort f2bf(float f)
{
    union { float f; unsigned u; } v; v.f = f;
    unsigned r = v.u + 0x7FFF + ((v.u >> 16) & 1);   // RNE
    return (ushort)(r >> 16);
}

__device__ inline unsigned cvtpk(float lo, float hi)
{
    unsigned r;
    asm("v_cvt_pk_bf16_f32 %0, %1, %2" : "=v"(r) : "v"(lo), "v"(hi));
    return r;
}

// ---------------------------------------------------------------------------
// prep1: zero cnt + conv_x + conv_wf (one kernel).
// ---------------------------------------------------------------------------
__global__ __launch_bounds__(256) void prep1(
    float4* __restrict__ cntz, int cnt4,
    const float* __restrict__ x, ushort* __restrict__ xb, int nx4,
    const float* __restrict__ W1, const float* __restrict__ root1,
    ushort* __restrict__ Wf1,
    const float* __restrict__ W2, const float* __restrict__ root2,
    ushort* __restrict__ Wf2)
{
    int tid = blockIdx.x * 256 + threadIdx.x;
    int stride = gridDim.x * 256;

    for (int i = tid; i < cnt4; i += stride)
        cntz[i] = make_float4(0.f, 0.f, 0.f, 0.f);

    for (int i = tid; i < nx4; i += stride) {
        float4 v = ((const float4*)x)[i];
        ushort4 o;
        o.x = f2bf(v.x); o.y = f2bf(v.y); o.z = f2bf(v.z); o.w = f2bf(v.w);
        ((ushort4*)xb)[i] = o;
    }

    const int WFN = 128 * 1152;
    for (int i = tid; i < 2 * WFN; i += stride) {
        int half = (i >= WFN);
        int j = half ? i - WFN : i;
        const float* W    = half ? W2 : W1;
        const float* root = half ? root2 : root1;
        ushort* Wf        = half ? Wf2 : Wf1;
        int f = j >> 9;
        int within = j & 511;
        int l = within >> 3;
        int jj = within & 7;
        int rs = f >> 5;
        int kk = (f >> 3) & 3;
        int n  = f & 7;
        int col = (n << 4) | (l & 15);
        int kl  = kk * 32 + (l >> 4) * 8 + jj;
        float v = (rs < 8) ? W[rs * 16384 + kl * 128 + col]
                           : root[kl * 128 + col];
        Wf[j] = f2bf(v);
    }
}

// ---------------------------------------------------------------------------
// CSR build chain
// ---------------------------------------------------------------------------
__global__ __launch_bounds__(256) void count_edges(
    const int* __restrict__ ei, const int* __restrict__ et,
    int* __restrict__ cnt, int E, int N)
{
    int e = blockIdx.x * 256 + threadIdx.x;
    if (e < E) {
        int d = ei[E + e];
        int r = et[e];
        atomicAdd(&cnt[r * N + d], 1);
    }
}

__global__ __launch_bounds__(256) void scan1f(
    const int* __restrict__ cnt, float* __restrict__ invc8,
    int* __restrict__ part, int* __restrict__ bsum, int N)
{
    __shared__ int tmp[256];
    int d = blockIdx.x * 256 + threadIdx.x;
    int s = 0;
    if (d < N) {
        #pragma unroll
        for (int r = 0; r < NREL; r++) {
            int c = cnt[r * N + d];
            s += c;
            invc8[(size_t)d * 8 + r] = (c > 0) ? 1.f / (float)c : 0.f;
        }
    }
    int v = s;
    tmp[threadIdx.x] = v;
    __syncthreads();
    for (int off = 1; off < 256; off <<= 1) {
        int t = (threadIdx.x >= off) ? tmp[threadIdx.x - off] : 0;
        __syncthreads();
        tmp[threadIdx.x] += t;
        __syncthreads();
    }
    if (d < N) part[d] = tmp[threadIdx.x] - v;
    if (threadIdx.x == 255) bsum[blockIdx.x] = tmp[255];
}

__global__ __launch_bounds__(1024) void scan2(int* __restrict__ bsum, int nb)
{
    __shared__ int tmp[1024];
    int tid = threadIdx.x;
    int v = (tid < nb) ? bsum[tid] : 0;
    tmp[tid] = v;
    __syncthreads();
    for (int off = 1; off < 1024; off <<= 1) {
        int t = (tid >= off) ? tmp[tid - off] : 0;
        __syncthreads();
        tmp[tid] += t;
        __syncthreads();
    }
    if (tid < nb) bsum[tid] = tmp[tid] - v;
}

__global__ __launch_bounds__(256) void scan3(
    const int* __restrict__ part, const int* __restrict__ bsum,
    int* __restrict__ rowptr, int* __restrict__ cursor, int n, int E)
{
    int i = blockIdx.x * 256 + threadIdx.x;
    if (i < n) {
        int v = part[i] + bsum[blockIdx.x];
        rowptr[i] = v;
        cursor[i] = v;
    }
    if (i == 0) rowptr[n] = E;
}

__global__ __launch_bounds__(256) void fill_csr(
    const int* __restrict__ ei, const int* __restrict__ et,
    int* __restrict__ cursor, int* __restrict__ spk, int E)
{
    int e = blockIdx.x * 256 + threadIdx.x;
    if (e < E) {
        int d = ei[E + e];
        int pos = atomicAdd(&cursor[d], 1);
        spk[pos] = (ei[e] << 8) | et[e];
    }
}

// ---------------------------------------------------------------------------
// FUSED gather + MFMA (+ layer-2 classifier), v8 (round-20 state, reverted
// from the round-21 fp8 experiment: e4m3's 3 mantissa bits compounded across
// both layers -> absmax 0.668 > 0.46. bf16 gather restored).
// ---------------------------------------------------------------------------
__global__ __launch_bounds__(1024, 8) void fused_layer(
    const ushort* __restrict__ Xb, const int* __restrict__ rowptr,
    const int* __restrict__ spk, const float* __restrict__ invc8,
    const ushort* __restrict__ Wf, const float* __restrict__ bias,
    float* __restrict__ Ofp, ushort* __restrict__ Obf,
    const float* __restrict__ Wc, const float* __restrict__ bc,
    float* __restrict__ outC, int N, int relu)
{
    __shared__ ushort lds[8 * 32 * 128];   // 64 KB A-tile; reused as embt
    __shared__ f32x4 pscr[2][512];         // 16 KB partial accumulators

    int wid  = threadIdx.x >> 6;           // 0..15
    int lane = threadIdx.x & 63;
    int blk0 = blockIdx.x * 32;
    int lane4 = lane << 2;

    // ---------------- phase 1: gather TWO rows per wave ----------------
    #pragma unroll 1
    for (int rr = 0; rr < 2; rr++) {
        int lrow32 = wid * 2 + rr;
        int d = blk0 + lrow32;

        float2 a0 = {0.f, 0.f}, a1 = {0.f, 0.f}, a2 = {0.f, 0.f}, a3 = {0.f, 0.f};
        float2 a4 = {0.f, 0.f}, a5 = {0.f, 0.f}, a6 = {0.f, 0.f}, a7 = {0.f, 0.f};

        #define ROWLD(SP) \
            (*(const unsigned*)((const char*)Xb + (unsigned)((SP) | lane4)))
        #define CONSUME(P, U)                                               \
        {                                                                   \
            union { unsigned u; float f; } lo, hi;                          \
            lo.u = (U) << 16; hi.u = (U) & 0xFFFF0000u;                     \
            switch ((P) & 0xFF) {                                           \
                case 0: a0.x += lo.f; a0.y += hi.f; break;                  \
                case 1: a1.x += lo.f; a1.y += hi.f; break;                  \
                case 2: a2.x += lo.f; a2.y += hi.f; break;                  \
                case 3: a3.x += lo.f; a3.y += hi.f; break;                  \
                case 4: a4.x += lo.f; a4.y += hi.f; break;                  \
                case 5: a5.x += lo.f; a5.y += hi.f; break;                  \
                case 6: a6.x += lo.f; a6.y += hi.f; break;                  \
                default: a7.x += lo.f; a7.y += hi.f; break;                 \
            }                                                               \
        }

        if (d < N) {
            int beg = rowptr[d], end = rowptr[d + 1];
            int i = beg;
            for (; i + 8 <= end; i += 8) {
                int pk8 = spk[i + (lane & 7)];
                int p0 = __builtin_amdgcn_readlane(pk8, 0);
                int p1 = __builtin_amdgcn_readlane(pk8, 1);
                int p2 = __builtin_amdgcn_readlane(pk8, 2);
                int p3 = __builtin_amdgcn_readlane(pk8, 3);
                int p4 = __builtin_amdgcn_readlane(pk8, 4);
                int p5 = __builtin_amdgcn_readlane(pk8, 5);
                int p6 = __builtin_amdgcn_readlane(pk8, 6);
                int p7 = __builtin_amdgcn_readlane(pk8, 7);
                unsigned u0 = ROWLD(p0 & 0xFFFFFF00);
                unsigned u1 = ROWLD(p1 & 0xFFFFFF00);
                unsigned u2 = ROWLD(p2 & 0xFFFFFF00);
                unsigned u3 = ROWLD(p3 & 0xFFFFFF00);
                unsigned u4 = ROWLD(p4 & 0xFFFFFF00);
                unsigned u5 = ROWLD(p5 & 0xFFFFFF00);
                unsigned u6 = ROWLD(p6 & 0xFFFFFF00);
                unsigned u7 = ROWLD(p7 & 0xFFFFFF00);
                CONSUME(p0, u0);
                CONSUME(p1, u1);
                CONSUME(p2, u2);
                CONSUME(p3, u3);
                CONSUME(p4, u4);
                CONSUME(p5, u5);
                CONSUME(p6, u6);
                CONSUME(p7, u7);
            }
            for (; i + 4 <= end; i += 4) {
                int pk4 = spk[i + (lane & 3)];
                int p0 = __builtin_amdgcn_readlane(pk4, 0);
                int p1 = __builtin_amdgcn_readlane(pk4, 1);
                int p2 = __builtin_amdgcn_readlane(pk4, 2);
                int p3 = __builtin_amdgcn_readlane(pk4, 3);
                unsigned u0 = ROWLD(p0 & 0xFFFFFF00);
                unsigned u1 = ROWLD(p1 & 0xFFFFFF00);
                unsigned u2 = ROWLD(p2 & 0xFFFFFF00);
                unsigned u3 = ROWLD(p3 & 0xFFFFFF00);
                CONSUME(p0, u0);
                CONSUME(p1, u1);
                CONSUME(p2, u2);
                CONSUME(p3, u3);
            }
            for (; i < end; i++) {
                int p = __builtin_amdgcn_readfirstlane(spk[i]);
                unsigned u = ROWLD(p & 0xFFFFFF00);
                CONSUME(p, u);
            }
        }
        #undef CONSUME
        #undef ROWLD

        f32x4 iv0 = {0.f, 0.f, 0.f, 0.f}, iv1 = {0.f, 0.f, 0.f, 0.f};
        if (d < N) {
            iv0 = *(const f32x4*)&invc8[(size_t)d * 8];
            iv1 = *(const f32x4*)&invc8[(size_t)d * 8 + 4];
        }
        unsigned swz = (unsigned)(lrow32 & 7) << 4;
        char* rowbase = (char*)lds + (lrow32 << 8);
        unsigned wroff = (((unsigned)lane << 2)) ^ swz;
        #define WR2(R, A, IV)                                               \
        {                                                                   \
            unsigned pk = cvtpk(A.x * (IV), A.y * (IV));                    \
            *(unsigned*)(rowbase + (R << 13) + wroff) = pk;                 \
        }
        WR2(0, a0, iv0[0]) WR2(1, a1, iv0[1]) WR2(2, a2, iv0[2]) WR2(3, a3, iv0[3])
        WR2(4, a4, iv1[0]) WR2(5, a5, iv1[1]) WR2(6, a6, iv1[2]) WR2(7, a7, iv1[3])
        #undef WR2
    }
    __syncthreads();

    // ---------------- phase 2: K-split MFMA, 2 row-groups per B ----------------
    int lrow = lane & 15;
    int kgrp = lane >> 4;
    unsigned swzR = (unsigned)(lrow & 7) << 4;
    const bf16x8* Wf8 = (const bf16x8*)Wf;
    int n0    = wid & 7;
    int upper = wid >> 3;

    f32x4 acc0 = {0.f, 0.f, 0.f, 0.f};
    f32x4 acc1 = {0.f, 0.f, 0.f, 0.f};
    const char* ldsb = (const char*)lds;

    int rs0 = upper * 4;
    #pragma unroll 1
    for (int rs = rs0; rs < rs0 + 4; rs++) {
        const bf16x8* Bp = Wf8 + (size_t)rs * 2048 + (size_t)n0 * 64 + lane;
        bf16x8 b0 = Bp[0];
        bf16x8 b1 = Bp[512];
        bf16x8 b2 = Bp[1024];
        bf16x8 b3 = Bp[1536];
        const char* ab0 = ldsb + (rs << 13) + ((0 + lrow) << 8);
        const char* ab1 = ldsb + (rs << 13) + ((16 + lrow) << 8);
        {
            bf16x8 a0 = *(const bf16x8*)(ab0 + ((unsigned)(0 * 64 + kgrp * 16) ^ swzR));
            bf16x8 a1 = *(const bf16x8*)(ab0 + ((unsigned)(1 * 64 + kgrp * 16) ^ swzR));
            bf16x8 a2 = *(const bf16x8*)(ab0 + ((unsigned)(2 * 64 + kgrp * 16) ^ swzR));
            bf16x8 a3 = *(const bf16x8*)(ab0 + ((unsigned)(3 * 64 + kgrp * 16) ^ swzR));
            acc0 = __builtin_amdgcn_mfma_f32_16x16x32_bf16(a0, b0, acc0, 0, 0, 0);
            acc0 = __builtin_amdgcn_mfma_f32_16x16x32_bf16(a1, b1, acc0, 0, 0, 0);
            acc0 = __builtin_amdgcn_mfma_f32_16x16x32_bf16(a2, b2, acc0, 0, 0, 0);
            acc0 = __builtin_amdgcn_mfma_f32_16x16x32_bf16(a3, b3, acc0, 0, 0, 0);
        }
        {
            bf16x8 a0 = *(const bf16x8*)(ab1 + ((unsigned)(0 * 64 + kgrp * 16) ^ swzR));
            bf16x8 a1 = *(const bf16x8*)(ab1 + ((unsigned)(1 * 64 + kgrp * 16) ^ swzR));
            bf16x8 a2 = *(const bf16x8*)(ab1 + ((unsigned)(2 * 64 + kgrp * 16) ^ swzR));
            bf16x8 a3 = *(const bf16x8*)(ab1 + ((unsigned)(3 * 64 + kgrp * 16) ^ swzR));
            acc1 = __builtin_amdgcn_mfma_f32_16x16x32_bf16(a0, b0, acc1, 0, 0, 0);
            acc1 = __builtin_amdgcn_mfma_f32_16x16x32_bf16(a1, b1, acc1, 0, 0, 0);
            acc1 = __builtin_amdgcn_mfma_f32_16x16x32_bf16(a2, b2, acc1, 0, 0, 0);
            acc1 = __builtin_amdgcn_mfma_f32_16x16x32_bf16(a3, b3, acc1, 0, 0, 0);
        }
    }
    {   // root source from global Xb
        int arow0 = blk0 + lrow;      if (arow0 >= N) arow0 = N - 1;
        int arow1 = blk0 + 16 + lrow; if (arow1 >= N) arow1 = N - 1;
        const ushort* A0 = Xb + (size_t)arow0 * 128;
        const ushort* A1 = Xb + (size_t)arow1 * 128;
        const bf16x8* Bp = Wf8 + (size_t)8 * 2048 + (size_t)n0 * 64 + lane;
        int kkb = upper * 2;
        bf16x8 b0 = Bp[(kkb + 0) * 512];
        bf16x8 b1 = Bp[(kkb + 1) * 512];
        bf16x8 a00 = *(const bf16x8*)(A0 + (kkb + 0) * 32 + kgrp * 8);
        bf16x8 a01 = *(const bf16x8*)(A0 + (kkb + 1) * 32 + kgrp * 8);
        bf16x8 a10 = *(const bf16x8*)(A1 + (kkb + 0) * 32 + kgrp * 8);
        bf16x8 a11 = *(const bf16x8*)(A1 + (kkb + 1) * 32 + kgrp * 8);
        acc0 = __builtin_amdgcn_mfma_f32_16x16x32_bf16(a00, b0, acc0, 0, 0, 0);
        acc0 = __builtin_amdgcn_mfma_f32_16x16x32_bf16(a01, b1, acc0, 0, 0, 0);
        acc1 = __builtin_amdgcn_mfma_f32_16x16x32_bf16(a10, b0, acc1, 0, 0, 0);
        acc1 = __builtin_amdgcn_mfma_f32_16x16x32_bf16(a11, b1, acc1, 0, 0, 0);
    }

    if (upper) {
        pscr[0][n0 * 64 + lane] = acc0;
        pscr[1][n0 * 64 + lane] = acc1;
    }
    __syncthreads();   // all A-tile reads complete after this

    if (!upper) {
        f32x4 p0 = pscr[0][n0 * 64 + lane];
        f32x4 p1 = pscr[1][n0 * 64 + lane];
        int col = n0 * 16 + lrow;
        float bv = bias[col];
        float* embt = (float*)lds;   // stride 132 (bank-conflict-free)
        #pragma unroll
        for (int rg = 0; rg < 2; rg++) {
            int lrowb = rg * 16 + kgrp * 4;
            f32x4 a = rg ? acc1 : acc0;
            f32x4 pp = rg ? p1 : p0;
            #pragma unroll
            for (int r = 0; r < 4; r++) {
                int row = blk0 + lrowb + r;
                float v = a[r] + pp[r] + bv;
                if (relu) v = fmaxf(v, 0.f);
                if (outC) embt[(lrowb + r) * 132 + col] = v;
                if (row < N) {
                    if (Ofp) Ofp[(size_t)row * 128 + col] = v;
                    if (Obf) Obf[(size_t)row * 128 + col] = f2bf(v);
                }
            }
        }
    }

    // ---------------- fused classifier (layer 2 only) ----------------
    if (outC) {
        __syncthreads();
        int t = threadIdx.x;
        if (t < 512) {
            int row = t >> 4;
            int c = t & 15;
            const float* er = (const float*)lds + row * 132;
            float acc2 = bc[c];
            #pragma unroll 8
            for (int k = 0; k < 128; k++) acc2 += er[k] * Wc[k * 16 + c];
            int grow = blk0 + row;
            if (grow < N) outC[(size_t)grow * 16 + c] = acc2;
        }
    }
}

static inline size_t align256(size_t x) { return (x + 255) & ~(size_t)255; }

extern "C" void kernel_launch(void* const* d_in, const int* in_sizes, int n_in,
                              void* d_out, int out_size, void* d_ws, size_t ws_size,
                              hipStream_t stream)
{
    const float* x     = (const float*)d_in[0];
    const int*   ei    = (const int*)d_in[1];
    const int*   et    = (const int*)d_in[2];
    const float* W1    = (const float*)d_in[3];
    const float* root1 = (const float*)d_in[4];
    const float* b1    = (const float*)d_in[5];
    const float* W2    = (const float*)d_in[6];
    const float* root2 = (const float*)d_in[7];
    const float* b2    = (const float*)d_in[8];
    const float* Wc    = (const float*)d_in[9];
    const float* bc    = (const float*)d_in[10];

    const int N = in_sizes[0] / 128;
    const int E = in_sizes[2];
    const int C = in_sizes[10];   // 16

    float* out = (float*)d_out;                 // [N,16]
    float* emb = out + (size_t)N * C;           // [N,128] fp32 (2nd output)

    size_t cntB  = align256((size_t)NREL * N * sizeof(int));
    size_t rpB   = align256((size_t)(N + 1) * sizeof(int));
    size_t curB  = align256((size_t)N * sizeof(int));
    size_t bsB   = align256((size_t)1024 * sizeof(int));
    size_t invB  = align256((size_t)N * 8 * sizeof(float));
    size_t spkB  = align256((size_t)E * sizeof(int));
    size_t xbB   = align256((size_t)N * 128 * sizeof(ushort));
    size_t wtB   = align256((size_t)128 * 1152 * sizeof(ushort));

    char* p = (char*)d_ws;
    int*    cnt    = (int*)p;      p += cntB;
    int*    rowptr = (int*)p;      p += rpB;
    int*    cursor = (int*)p;      p += curB;
    int*    part   = (int*)p;      p += curB;
    int*    bsum   = (int*)p;      p += bsB;
    float*  invc8  = (float*)p;    p += invB;
    int*    spk    = (int*)p;      p += spkB;
    ushort* xb     = (ushort*)p;   p += xbB;
    ushort* hb     = (ushort*)p;   p += xbB;
    ushort* Wf1    = (ushort*)p;   p += wtB;
    ushort* Wf2    = (ushort*)p;

    dim3 blk(256);
    int gE    = (E + 255) / 256;
    int gN    = (N + 255) / 256;
    int gFus  = (N + 31) / 32;       // 1563
    long long cnt4 = (long long)NREL * N / 4;
    int nx4 = N * 32;

    // ---- prep: zeros + bf16 conversions (one kernel) ----
    prep1<<<2048, blk, 0, stream>>>((float4*)cnt, (int)cnt4,
                                    x, xb, nx4,
                                    W1, root1, Wf1, W2, root2, Wf2);

    // ---- CSR build ----
    count_edges<<<gE, blk, 0, stream>>>(ei, et, cnt, E, N);
    scan1f<<<gN, blk, 0, stream>>>(cnt, invc8, part, bsum, N);
    scan2<<<1, 1024, 0, stream>>>(bsum, gN);
    scan3<<<gN, blk, 0, stream>>>(part, bsum, rowptr, cursor, N, E);
    fill_csr<<<gE, blk, 0, stream>>>(ei, et, cursor, spk, E);

    // ---- layer 1: fused gather+GEMM -> hb (bf16, relu) ----
    fused_layer<<<gFus, dim3(1024), 0, stream>>>(
        xb, rowptr, spk, invc8, Wf1, b1, nullptr, hb,
        nullptr, nullptr, nullptr, N, 1);

    // ---- layer 2: fused gather+GEMM+classifier -> emb + out ----
    fused_layer<<<gFus, dim3(1024), 0, stream>>>(
        hb, rowptr, spk, invc8, Wf2, b2, emb, nullptr,
        Wc, bc, out, N, 0);
}